// Round 1
// baseline (74.575 us; speedup 1.0000x reference)
//
#include <hip/hip_runtime.h>
#include <hip/hip_bf16.h>

#define NFEAT 40
#define EMB   64
#define ATT   32
#define NPAIR 780
#define NPADP 784
#define NMT   49      // 784/16 M-tiles of 16 pairs
#define XF_S  68      // fp32 x LDS stride (floats), +4 pad
#define XH_S  72      // bf16 x LDS stride (elems), +8 pad

typedef __attribute__((ext_vector_type(8))) short bf16x8;
typedef __attribute__((ext_vector_type(4))) float f32x4;

// fp32 -> bf16 bits, round-nearest-even (inputs finite)
__device__ __forceinline__ unsigned f2bf_bits(float f) {
  unsigned u = __float_as_uint(f);
  return (u + 0x7fffu + ((u >> 16) & 1u)) >> 16;
}

template <int CTRL>
__device__ __forceinline__ float dpp_add_f(float v) {
  int t = __builtin_amdgcn_update_dpp(0, __float_as_int(v), CTRL, 0xF, 0xF, true);
  return v + __int_as_float(t);
}
// sum across each 16-lane row (DPP row_ror 8/4/2/1) — all 16 lanes get the sum
__device__ __forceinline__ float rowsum16(float v) {
  v = dpp_add_f<0x128>(v);
  v = dpp_add_f<0x124>(v);
  v = dpp_add_f<0x122>(v);
  v = dpp_add_f<0x121>(v);
  return v;
}

// compile-time pair index -> (i, j); folds after full unroll
__device__ constexpr int cpair_i(int p) {
  if (p >= NPAIR) return 0;
  int i = 0, off = 0;
  while (off + (NFEAT - 1 - i) <= p) { off += NFEAT - 1 - i; ++i; }
  return i;
}
__device__ constexpr int cpair_j(int p) {
  if (p >= NPAIR) return 0;
  int i = cpair_i(p);
  int off = i * (NFEAT - 1) - i * (i - 1) / 2;
  return i + 1 + (p - off);
}

// attention-weighted pair pooling over chunk range [C0,C1) (4 pairs/chunk),
// all indices compile-time so xr[] stays in registers
template <int C0, int C1>
__device__ __forceinline__ float pooled_range(const float* ep, const float (&xr)[NFEAT]) {
  float acc = 0.f;
#pragma unroll
  for (int c = C0; c < C1; c++) {
    float4 e4 = *(const float4*)&ep[4 * c];
#pragma unroll
    for (int t = 0; t < 4; t++) {
      const int p = 4 * c + t;
      const int i = cpair_i(p), j = cpair_j(p);
      float e = (t == 0) ? e4.x : (t == 1) ? e4.y : (t == 2) ? e4.z : e4.w;
      acc = fmaf(e, xr[i] * xr[j], acc);
    }
  }
  return acc;
}

extern "C" __global__ __launch_bounds__(256)
void afm_kernel(const float* __restrict__ xg, const float* __restrict__ Wg,
                const float* __restrict__ bg, const float* __restrict__ hg,
                const float* __restrict__ pg, float* __restrict__ outg) {
  __shared__ float xf[NFEAT * XF_S];
  __shared__ unsigned short xh[NFEAT * XH_S];
  __shared__ unsigned short prt[NPADP];
  __shared__ float ep[NPADP];
  __shared__ float pp[256];
  __shared__ float redz[4];

  const int tid  = threadIdx.x;
  const int bb   = blockIdx.x;
  const int lane = tid & 63, wid = tid >> 6;
  const int l15  = lane & 15, hk = lane >> 4;

  // ---- stage 0: x -> LDS (fp32 + bf16 copies) ----
  const float4* xsrc = (const float4*)(xg + (size_t)bb * (NFEAT * EMB));
  for (int f = tid; f < NFEAT * EMB / 4; f += 256) {
    float4 v = xsrc[f];
    int row = f >> 4, c = (f & 15) * 4;
    *(float4*)&xf[row * XF_S + c] = v;
    unsigned lo = f2bf_bits(v.x) | (f2bf_bits(v.y) << 16);
    unsigned hi = f2bf_bits(v.z) | (f2bf_bits(v.w) << 16);
    *(uint2*)&xh[row * XH_S + c] = make_uint2(lo, hi);
  }
  // pair table (i | j<<8)
  for (int p = tid; p < NPADP; p += 256) {
    int i = 0, off = 0, j = 0;
    if (p < NPAIR) {
      while (off + (NFEAT - 1 - i) <= p) { off += NFEAT - 1 - i; ++i; }
      j = i + 1 + (p - off);
    }
    prt[p] = (unsigned short)(i | (j << 8));
  }
  if (tid < NPADP - NPAIR) ep[NPAIR + tid] = 0.f;

  // ---- W fragments (B operand, registers), bias/h ----
  bf16x8 wf[2][2];  // [ntile][kk]
#pragma unroll
  for (int nt = 0; nt < 2; nt++)
#pragma unroll
    for (int kk = 0; kk < 2; kk++) {
      bf16x8 r;
#pragma unroll
      for (int t = 0; t < 8; t++)
        r[t] = (short)f2bf_bits(Wg[(kk * 32 + hk * 8 + t) * ATT + nt * 16 + l15]);
      wf[nt][kk] = r;
    }
  const float bias0 = bg[l15], bias1 = bg[16 + l15];
  const float h0 = hg[l15], h1 = hg[16 + l15];

  __syncthreads();

  // ---- stage 1: pair-GEMM scores via MFMA + online epilogue ----
  for (int m = wid; m < NMT; m += 4) {
    const int p0 = m * 16;
    const unsigned pij = prt[p0 + l15];
    const int ai = pij & 0xFF, aj = pij >> 8;
    f32x4 acc0 = {0.f, 0.f, 0.f, 0.f};
    f32x4 acc1 = {0.f, 0.f, 0.f, 0.f};
#pragma unroll
    for (int kk = 0; kk < 2; kk++) {
      const uint4 xi = *(const uint4*)&xh[ai * XH_S + kk * 32 + hk * 8];
      const uint4 xj = *(const uint4*)&xh[aj * XH_S + kk * 32 + hk * 8];
      bf16x8 af;
#pragma unroll
      for (int d = 0; d < 4; d++) {
        unsigned wi = ((const unsigned*)&xi)[d];
        unsigned wj = ((const unsigned*)&xj)[d];
        float lo = __uint_as_float(wi << 16) * __uint_as_float(wj << 16);
        float hi = __uint_as_float(wi & 0xFFFF0000u) * __uint_as_float(wj & 0xFFFF0000u);
        af[2 * d]     = (short)f2bf_bits(lo);
        af[2 * d + 1] = (short)f2bf_bits(hi);
      }
      acc0 = __builtin_amdgcn_mfma_f32_16x16x32_bf16(af, wf[0][kk], acc0, 0, 0, 0);
      acc1 = __builtin_amdgcn_mfma_f32_16x16x32_bf16(af, wf[1][kk], acc1, 0, 0, 0);
    }
#pragma unroll
    for (int reg = 0; reg < 4; reg++) {
      float v = fmaxf(acc0[reg] + bias0, 0.f) * h0 + fmaxf(acc1[reg] + bias1, 0.f) * h1;
      v = rowsum16(v);
      if (l15 == 0) {
        int p = p0 + hk * 4 + reg;
        if (p < NPAIR) ep[p] = __expf(v);
      }
    }
  }
  __syncthreads();

  // ---- softmax denominator ----
  float z = ep[tid] + ep[tid + 256] + ep[tid + 512] +
            ((tid < NPAIR - 768) ? ep[768 + tid] : 0.f);
  z = rowsum16(z);
  z += __shfl_xor(z, 16, 64);
  z += __shfl_xor(z, 32, 64);
  if (lane == 0) redz[wid] = z;

  // ---- stage 3: attention-weighted pooling (x register-cached, e = lane) ----
  float xr[NFEAT];
#pragma unroll
  for (int r = 0; r < NFEAT; r++) xr[r] = xf[r * XF_S + lane];
  float part;
  if (wid == 0)      part = pooled_range<0, 49>(ep, xr);
  else if (wid == 1) part = pooled_range<49, 98>(ep, xr);
  else if (wid == 2) part = pooled_range<98, 147>(ep, xr);
  else               part = pooled_range<147, 196>(ep, xr);
  pp[tid] = part;
  __syncthreads();

  if (wid == 0) {
    float t = pp[lane] + pp[lane + 64] + pp[lane + 128] + pp[lane + 192];
    t *= pg[lane];             // p-vector dot (p == ones, but use the input)
    t = rowsum16(t);
    t += __shfl_xor(t, 16, 64);
    t += __shfl_xor(t, 32, 64);
    if (lane == 0) {
      float Z = redz[0] + redz[1] + redz[2] + redz[3];
      outg[bb] = t / Z;
    }
  }
}

extern "C" void kernel_launch(void* const* d_in, const int* in_sizes, int n_in,
                              void* d_out, int out_size, void* d_ws, size_t ws_size,
                              hipStream_t stream) {
  const float* xg = (const float*)d_in[0];
  const float* Wg = (const float*)d_in[1];
  const float* bg = (const float*)d_in[2];
  const float* hg = (const float*)d_in[3];
  const float* pg = (const float*)d_in[4];
  float* outg = (float*)d_out;
  const int Bn = in_sizes[0] / (NFEAT * EMB);
  afm_kernel<<<dim3(Bn), dim3(256), 0, stream>>>(xg, Wg, bg, hg, pg, outg);
}

// Round 2
// 46.239 us; speedup vs baseline: 1.6128x; 1.6128x over previous
//
#include <hip/hip_runtime.h>

#define NFEAT 40
#define EMB   64
#define ATT   32
#define NPAIR 780
#define NPADP 784
#define NMT   49      // 784/16 M-tiles of 16 pairs
#define XH_S  72      // fp16 x LDS stride (elems), +8 pad

typedef __attribute__((ext_vector_type(8))) _Float16 f16x8;
typedef __attribute__((ext_vector_type(4))) _Float16 f16x4;
typedef __attribute__((ext_vector_type(4))) float f32x4;

template <int CTRL>
__device__ __forceinline__ float dpp_add_f(float v) {
  int t = __builtin_amdgcn_update_dpp(0, __float_as_int(v), CTRL, 0xF, 0xF, true);
  return v + __int_as_float(t);
}
// sum across each 16-lane row (DPP row_ror 8/4/2/1) — all 16 lanes get the sum
__device__ __forceinline__ float rowsum16(float v) {
  v = dpp_add_f<0x128>(v);
  v = dpp_add_f<0x124>(v);
  v = dpp_add_f<0x122>(v);
  v = dpp_add_f<0x121>(v);
  return v;
}

__device__ __forceinline__ int pair_off(int i) {  // pairs before row i
  return 39 * i - (i * (i - 1)) / 2;
}

extern "C" __global__ __launch_bounds__(256)
void afm_kernel(const float* __restrict__ xg, const float* __restrict__ Wg,
                const float* __restrict__ bg, const float* __restrict__ hg,
                const float* __restrict__ pg, float* __restrict__ outg) {
  __shared__ __align__(16) _Float16 xh[NFEAT * XH_S];
  __shared__ unsigned short prt[NPADP];
  __shared__ float red[4][2];

  const int tid  = threadIdx.x;
  const int bb   = blockIdx.x;
  const int lane = tid & 63, wid = tid >> 6;
  const int l15  = lane & 15, hk = lane >> 4;

  // ---- stage 0: x -> fp16 LDS (RNE casts, one-time) ----
  const float4* xsrc = (const float4*)(xg + (size_t)bb * (NFEAT * EMB));
  for (int f = tid; f < NFEAT * EMB / 4; f += 256) {
    float4 v = xsrc[f];
    int row = f >> 4, c = (f & 15) * 4;
    f16x4 h4 = {(_Float16)v.x, (_Float16)v.y, (_Float16)v.z, (_Float16)v.w};
    *(f16x4*)&xh[row * XH_S + c] = h4;
  }
  // pair table (i | j<<8), closed-form + integer fixup
  for (int p = tid; p < NPADP; p += 256) {
    int i = 0, j = 0;
    if (p < NPAIR) {
      i = (int)((79.0f - sqrtf(6241.0f - 8.0f * (float)p)) * 0.5f);
      if (i < 0) i = 0;
      while (pair_off(i + 1) <= p) ++i;
      while (pair_off(i) > p) --i;
      j = i + 1 + (p - pair_off(i));
    }
    prt[p] = (unsigned short)(i | (j << 8));
  }

  // ---- W fragments (B operand, registers); n-tile 2 col 0 = p vector ----
  f16x8 wf0[2], wf1[2], wf2[2];
#pragma unroll
  for (int kk = 0; kk < 2; kk++) {
    f16x8 r0, r1, r2;
#pragma unroll
    for (int t = 0; t < 8; t++) {
      int krow = kk * 32 + hk * 8 + t;
      r0[t] = (_Float16)Wg[krow * ATT + l15];
      r1[t] = (_Float16)Wg[krow * ATT + 16 + l15];
      _Float16 pv = (_Float16)pg[krow];
      r2[t] = (l15 == 0) ? pv : (_Float16)0.f;
    }
    wf0[kk] = r0; wf1[kk] = r1; wf2[kk] = r2;
  }
  const float bias0 = bg[l15], bias1 = bg[16 + l15];
  const float h0 = hg[l15], h1 = hg[16 + l15];

  __syncthreads();

  // ---- stage 1: pair-GEMM scores + fused s_p column + online exp-sums ----
  float sum_e = 0.f, sum_es = 0.f;
  for (int m = wid; m < NMT; m += 4) {
    const int p0 = m * 16;
    const unsigned pij = prt[p0 + l15];
    const int ai = pij & 0xFF, aj = pij >> 8;
    f32x4 acc0 = {0.f, 0.f, 0.f, 0.f};
    f32x4 acc1 = {0.f, 0.f, 0.f, 0.f};
    f32x4 acc2 = {0.f, 0.f, 0.f, 0.f};
#pragma unroll
    for (int kk = 0; kk < 2; kk++) {
      const f16x8 xi = *(const f16x8*)&xh[ai * XH_S + kk * 32 + hk * 8];
      const f16x8 xj = *(const f16x8*)&xh[aj * XH_S + kk * 32 + hk * 8];
      f16x8 af = xi * xj;  // 4x v_pk_mul_f16
      acc0 = __builtin_amdgcn_mfma_f32_16x16x32_f16(af, wf0[kk], acc0, 0, 0, 0);
      acc1 = __builtin_amdgcn_mfma_f32_16x16x32_f16(af, wf1[kk], acc1, 0, 0, 0);
      acc2 = __builtin_amdgcn_mfma_f32_16x16x32_f16(af, wf2[kk], acc2, 0, 0, 0);
    }
#pragma unroll
    for (int reg = 0; reg < 4; reg++) {
      float va = fmaxf(acc0[reg] + bias0, 0.f);
      float vb = fmaxf(acc1[reg] + bias1, 0.f);
      float v = rowsum16(fmaf(va, h0, vb * h1));
      int p = p0 + hk * 4 + reg;
      if (l15 == 0 && p < NPAIR) {
        float e = __expf(v);
        sum_e += e;
        sum_es = fmaf(e, acc2[reg], sum_es);  // acc2[reg] = s_p = ewp_p . p
      }
    }
  }

  // ---- final: cross-lane (holders at l15==0) + cross-wave reduce ----
  sum_e  += __shfl_xor(sum_e, 16, 64);
  sum_e  += __shfl_xor(sum_e, 32, 64);
  sum_es += __shfl_xor(sum_es, 16, 64);
  sum_es += __shfl_xor(sum_es, 32, 64);
  if (lane == 0) { red[wid][0] = sum_e; red[wid][1] = sum_es; }
  __syncthreads();
  if (tid == 0) {
    float Z = red[0][0] + red[1][0] + red[2][0] + red[3][0];
    float S = red[0][1] + red[1][1] + red[2][1] + red[3][1];
    outg[bb] = S / Z;
  }
}

extern "C" void kernel_launch(void* const* d_in, const int* in_sizes, int n_in,
                              void* d_out, int out_size, void* d_ws, size_t ws_size,
                              hipStream_t stream) {
  const float* xg = (const float*)d_in[0];
  const float* Wg = (const float*)d_in[1];
  const float* bg = (const float*)d_in[2];
  const float* hg = (const float*)d_in[3];
  const float* pg = (const float*)d_in[4];
  float* outg = (float*)d_out;
  const int Bn = in_sizes[0] / (NFEAT * EMB);
  afm_kernel<<<dim3(Bn), dim3(256), 0, stream>>>(xg, Wg, bg, hg, pg, outg);
}

// Round 3
// 37.598 us; speedup vs baseline: 1.9835x; 1.2298x over previous
//
#include <hip/hip_runtime.h>

#define NFEAT 40
#define EMB   64
#define ATT   32
#define NPAIR 780
#define NPADP 784
#define NMT   49      // 784/16 M-tiles of 16 pairs
#define XH_S  72      // fp16 x LDS stride (elems) -> 144 B row stride

typedef __attribute__((ext_vector_type(8))) _Float16 f16x8;
typedef __attribute__((ext_vector_type(4))) _Float16 f16x4;
typedef __attribute__((ext_vector_type(4))) float f32x4;

template <int CTRL>
__device__ __forceinline__ float dpp_add_f(float v) {
  int t = __builtin_amdgcn_update_dpp(0, __float_as_int(v), CTRL, 0xF, 0xF, true);
  return v + __int_as_float(t);
}
__device__ __forceinline__ float rowsum16(float v) {
  v = dpp_add_f<0x128>(v);
  v = dpp_add_f<0x124>(v);
  v = dpp_add_f<0x122>(v);
  v = dpp_add_f<0x121>(v);
  return v;
}

__device__ __forceinline__ int pair_off(int i) { return 39 * i - (i * (i - 1)) / 2; }

extern "C" __global__ __launch_bounds__(256)
void afm_kernel(const float* __restrict__ xg, const float* __restrict__ Wg,
                const float* __restrict__ bg, const float* __restrict__ hg,
                const float* __restrict__ pg, float* __restrict__ outg, int nbatch) {
  __shared__ __align__(16) _Float16 xh[NFEAT * XH_S];
  __shared__ unsigned prt[NPADP];
  __shared__ float red[4][2];

  const int tid  = threadIdx.x;
  const int lane = tid & 63, wid = tid >> 6;
  const int l15  = lane & 15, hk = lane >> 4;

  // ---- once per block: pair table as packed LDS byte offsets ----
  for (int p = tid; p < NPADP; p += 256) {
    int i = 0, j = 0;
    if (p < NPAIR) {
      i = (int)((79.0f - sqrtf(6241.0f - 8.0f * (float)p)) * 0.5f);
      if (i < 0) i = 0;
      while (pair_off(i + 1) <= p) ++i;
      while (pair_off(i) > p) --i;
      j = i + 1 + (p - pair_off(i));
    }
    prt[p] = (unsigned)(i * 144) | ((unsigned)(j * 144) << 16);
  }

  // ---- once per block: W fragments (now the A operand), p in row 0 of wf2 ----
  f16x8 wf0[2], wf1[2], wf2[2];
#pragma unroll
  for (int kk = 0; kk < 2; kk++) {
    f16x8 r0, r1, r2;
#pragma unroll
    for (int t = 0; t < 8; t++) {
      int krow = kk * 32 + hk * 8 + t;
      r0[t] = (_Float16)Wg[krow * ATT + l15];
      r1[t] = (_Float16)Wg[krow * ATT + 16 + l15];
      _Float16 pv = (_Float16)pg[krow];
      r2[t] = (l15 == 0) ? pv : (_Float16)0.f;
    }
    wf0[kk] = r0; wf1[kk] = r1; wf2[kk] = r2;
  }
  // per-lane bias/h for att rows hk*4+r (acc0) and 16+hk*4+r (acc1)
  const float4 b0 = *(const float4*)&bg[hk * 4];
  const float4 b1 = *(const float4*)&bg[16 + hk * 4];
  const float4 h0 = *(const float4*)&hg[hk * 4];
  const float4 h1 = *(const float4*)&hg[16 + hk * 4];

  // ---- 2 batches per block ----
  for (int it = 0; it < 2; it++) {
    const int bb = blockIdx.x * 2 + it;
    if (bb >= nbatch) break;

    // stage x -> fp16 LDS
    const float4* xsrc = (const float4*)(xg + (size_t)bb * (NFEAT * EMB));
    for (int f = tid; f < NFEAT * EMB / 4; f += 256) {
      float4 v = xsrc[f];
      int row = f >> 4, c = (f & 15) * 4;
      f16x4 h4 = {(_Float16)v.x, (_Float16)v.y, (_Float16)v.z, (_Float16)v.w};
      *(f16x4*)&xh[row * XH_S + c] = h4;
    }
    __syncthreads();

    float sum_e = 0.f, sum_es = 0.f;
    for (int m = wid; m < NMT; m += 4) {
      const int p0 = m * 16;
      const unsigned pij  = prt[p0 + l15];
      const unsigned offi = (pij & 0xFFFFu) + hk * 16;
      const unsigned offj = (pij >> 16) + hk * 16;
      f32x4 acc0 = {0.f, 0.f, 0.f, 0.f};
      f32x4 acc1 = {0.f, 0.f, 0.f, 0.f};
      f32x4 acc2 = {0.f, 0.f, 0.f, 0.f};
#pragma unroll
      for (int kk = 0; kk < 2; kk++) {
        const f16x8 xi = *(const f16x8*)((const char*)xh + offi + kk * 64);
        const f16x8 xj = *(const f16x8*)((const char*)xh + offj + kk * 64);
        f16x8 af = xi * xj;  // 4x v_pk_mul_f16
        acc0 = __builtin_amdgcn_mfma_f32_16x16x32_f16(wf0[kk], af, acc0, 0, 0, 0);
        acc1 = __builtin_amdgcn_mfma_f32_16x16x32_f16(wf1[kk], af, acc1, 0, 0, 0);
        acc2 = __builtin_amdgcn_mfma_f32_16x16x32_f16(wf2[kk], af, acc2, 0, 0, 0);
      }
      // logit for pair p0+l15: in-lane 8 atts, then cross-group sum
      float v = 0.f;
      v = fmaf(fmaxf(acc0[0] + b0.x, 0.f), h0.x, v);
      v = fmaf(fmaxf(acc0[1] + b0.y, 0.f), h0.y, v);
      v = fmaf(fmaxf(acc0[2] + b0.z, 0.f), h0.z, v);
      v = fmaf(fmaxf(acc0[3] + b0.w, 0.f), h0.w, v);
      v = fmaf(fmaxf(acc1[0] + b1.x, 0.f), h1.x, v);
      v = fmaf(fmaxf(acc1[1] + b1.y, 0.f), h1.y, v);
      v = fmaf(fmaxf(acc1[2] + b1.z, 0.f), h1.z, v);
      v = fmaf(fmaxf(acc1[3] + b1.w, 0.f), h1.w, v);
      v += __shfl_xor(v, 16, 64);
      v += __shfl_xor(v, 32, 64);
      float e = (p0 + l15 < NPAIR) ? __expf(v) : 0.f;
      sum_e += e;                              // counted 4x (hk groups) -> /4 later
      sum_es = fmaf(e, acc2[0], sum_es);       // acc2[0]==0 unless hk==0
    }

    // wave reduce then block reduce
    sum_e = rowsum16(sum_e);
    sum_e += __shfl_xor(sum_e, 16, 64);
    sum_e += __shfl_xor(sum_e, 32, 64);
    sum_es = rowsum16(sum_es);
    sum_es += __shfl_xor(sum_es, 16, 64);
    sum_es += __shfl_xor(sum_es, 32, 64);
    if (lane == 0) { red[wid][0] = sum_e; red[wid][1] = sum_es; }
    __syncthreads();
    if (tid == 0) {
      float Z = (red[0][0] + red[1][0] + red[2][0] + red[3][0]) * 0.25f;
      float S = red[0][1] + red[1][1] + red[2][1] + red[3][1];
      outg[bb] = S / Z;
    }
    // xh reads of this batch happen-before the red-write sync above, so
    // next iteration's staging is safe.
  }
}

extern "C" void kernel_launch(void* const* d_in, const int* in_sizes, int n_in,
                              void* d_out, int out_size, void* d_ws, size_t ws_size,
                              hipStream_t stream) {
  const float* xg = (const float*)d_in[0];
  const float* Wg = (const float*)d_in[1];
  const float* bg = (const float*)d_in[2];
  const float* hg = (const float*)d_in[3];
  const float* pg = (const float*)d_in[4];
  float* outg = (float*)d_out;
  const int Bn = in_sizes[0] / (NFEAT * EMB);
  const int nblk = (Bn + 1) / 2;
  afm_kernel<<<dim3(nblk), dim3(256), 0, stream>>>(xg, Wg, bg, hg, pg, outg, Bn);
}